// Round 6
// baseline (294.120 us; speedup 1.0000x reference)
//
#include <hip/hip_runtime.h>

#define IN_C 8
#define HID_C 64
#define OUT_C 32

typedef unsigned int u32;
typedef unsigned short u16;

__device__ __forceinline__ float bf_lo(u32 u) {
    union { u32 i; float f; } c; c.i = u << 16; return c.f;
}
__device__ __forceinline__ float bf_hi(u32 u) {
    union { u32 i; float f; } c; c.i = u & 0xffff0000u; return c.f;
}
__device__ __forceinline__ u16 f2bf(float v) {          // RNE fp32 -> bf16
    union { float f; u32 i; } c; c.f = v;
    u32 r = c.i + 0x7fffu + ((c.i >> 16) & 1u);
    return (u16)(r >> 16);
}

// ---------------------------------------------------------------------------
// K1: degree histogram + per-edge rank (returning atomics), 8 edges/thread.
// ---------------------------------------------------------------------------
__global__ __launch_bounds__(256) void hist_kernel(
    const int* __restrict__ dst, int* __restrict__ cnt,
    int* __restrict__ erank, int E)
{
    int i = blockIdx.x * blockDim.x + threadIdx.x;
    int e0 = i * 8;
    if (e0 + 7 < E) {
        int4 a = *(const int4*)(dst + e0);
        int4 b = *(const int4*)(dst + e0 + 4);
        int4 ra, rb;
        ra.x = atomicAdd(&cnt[a.x], 1); ra.y = atomicAdd(&cnt[a.y], 1);
        ra.z = atomicAdd(&cnt[a.z], 1); ra.w = atomicAdd(&cnt[a.w], 1);
        rb.x = atomicAdd(&cnt[b.x], 1); rb.y = atomicAdd(&cnt[b.y], 1);
        rb.z = atomicAdd(&cnt[b.z], 1); rb.w = atomicAdd(&cnt[b.w], 1);
        *(int4*)(erank + e0) = ra;
        *(int4*)(erank + e0 + 4) = rb;
    } else {
        for (int e = e0; e < E; ++e)
            erank[e] = atomicAdd(&cnt[dst[e]], 1);
    }
}

// ---------------------------------------------------------------------------
// K2: CSR bases via wave scan; writes base[] (for fill) and meta[]=(base,cnt).
// ---------------------------------------------------------------------------
__global__ __launch_bounds__(256) void base_kernel(
    const int* __restrict__ cnt, int* __restrict__ base,
    int2* __restrict__ meta, int* __restrict__ cursor, int N)
{
    int n = blockIdx.x * blockDim.x + threadIdx.x;
    int lane = threadIdx.x & 63;
    int c = (n < N) ? cnt[n] : 0;

    int v = c;
    #pragma unroll
    for (int off = 1; off < 64; off <<= 1) {
        int t = __shfl_up(v, off);
        if (lane >= off) v += t;
    }
    int total = __shfl(v, 63);
    int waveBase = 0;
    if (lane == 63 && total > 0) waveBase = atomicAdd(cursor, total);
    waveBase = __shfl(waveBase, 63);

    if (n < N) {
        int b = waveBase + v - c;
        base[n] = b;
        meta[n] = make_int2(b, c);
    }
}

// ---------------------------------------------------------------------------
// K3: atomic-free CSR fill, 8 edges/thread, non-temporal scattered stores.
// ---------------------------------------------------------------------------
__global__ __launch_bounds__(256) void fill_kernel(
    const int* __restrict__ src, const int* __restrict__ dst,
    const int* __restrict__ erank, const int* __restrict__ base,
    int* __restrict__ csr_src, int E)
{
    int i = blockIdx.x * blockDim.x + threadIdx.x;
    int e0 = i * 8;
    if (e0 + 7 < E) {
        int4 s0 = *(const int4*)(src + e0), s1 = *(const int4*)(src + e0 + 4);
        int4 d0 = *(const int4*)(dst + e0), d1 = *(const int4*)(dst + e0 + 4);
        int4 r0 = *(const int4*)(erank + e0), r1 = *(const int4*)(erank + e0 + 4);
        __builtin_nontemporal_store(s0.x, &csr_src[base[d0.x] + r0.x]);
        __builtin_nontemporal_store(s0.y, &csr_src[base[d0.y] + r0.y]);
        __builtin_nontemporal_store(s0.z, &csr_src[base[d0.z] + r0.z]);
        __builtin_nontemporal_store(s0.w, &csr_src[base[d0.w] + r0.w]);
        __builtin_nontemporal_store(s1.x, &csr_src[base[d1.x] + r1.x]);
        __builtin_nontemporal_store(s1.y, &csr_src[base[d1.y] + r1.y]);
        __builtin_nontemporal_store(s1.z, &csr_src[base[d1.z] + r1.z]);
        __builtin_nontemporal_store(s1.w, &csr_src[base[d1.w] + r1.w]);
    } else {
        for (int e = e0; e < E; ++e)
            __builtin_nontemporal_store(src[e], &csr_src[base[dst[e]] + erank[e]]);
    }
}

// ---------------------------------------------------------------------------
// K4: fused layer-1 + both layer-2 projections. One wave per node,
// grid-strided, no barriers (all LDS is wave-local, in-order DS).
// Gather: (slot = l>>3, ch = l&7) scalar loads; 3-shuffle xor reduce;
// mean staged via 8-float LDS write + 2 uniform float4 broadcasts.
// W2 columns in registers; p stored as bf16.
// ---------------------------------------------------------------------------
__global__ __launch_bounds__(256) void layer1_kernel(
    const float* __restrict__ x, const int* __restrict__ csr_src,
    const int2* __restrict__ meta,
    const float* __restrict__ W1l, const float* __restrict__ W1r,
    const float* __restrict__ b1,
    const float* __restrict__ W2l, const float* __restrict__ W2r,
    const float* __restrict__ b2,
    u16* __restrict__ pb, float* __restrict__ out, int N, int nwaves)
{
    __shared__ float hl[4][HID_C];
    __shared__ float mbuf[4][8];
    int tid = threadIdx.x;
    int w = tid >> 6;
    int l = tid & 63;
    int waveId = blockIdx.x * 4 + w;

    float4 w1l_a = *(const float4*)(W1l + l * IN_C);
    float4 w1l_b = *(const float4*)(W1l + l * IN_C + 4);
    float4 w1r_a = *(const float4*)(W1r + l * IN_C);
    float4 w1r_b = *(const float4*)(W1r + l * IN_C + 4);
    int c = l & 31;
    const float* W2 = (l < 32) ? W2l : W2r;
    float4 w2q[16];
    #pragma unroll
    for (int r = 0; r < 16; ++r)
        w2q[r] = *(const float4*)(W2 + c * HID_C + r * 4);
    float bias1 = b1[l];
    float bias2 = (l < 32) ? 0.0f : b2[c];

    int slot = l >> 3;
    int ch = l & 7;

    for (int n = waveId; n < N; n += nwaves) {
        int2 m = meta[n];                       // (base, deg) in one 8B load
        float icnt = 1.0f / (float)max(m.y, 1);

        // neighbor mean: scalar gather, 8 slots x 8 channels
        float g = 0.f;
        for (int it = slot; it < m.y; it += 8)
            g += x[(size_t)csr_src[m.x + it] * IN_C + ch];
        g += __shfl_xor(g, 8);
        g += __shfl_xor(g, 16);
        g += __shfl_xor(g, 32);
        if (l < 8) mbuf[w][l] = g * icnt;       // wave-local, in-order DS
        float4 mk0 = *(const float4*)&mbuf[w][0];
        float4 mk1 = *(const float4*)&mbuf[w][4];

        float4 xa = *(const float4*)(x + (size_t)n * IN_C);
        float4 xb = *(const float4*)(x + (size_t)n * IN_C + 4);
        float ha = bias1 + mk0.x * w1l_a.x + xa.x * w1r_a.x
                         + mk0.z * w1l_a.z + xa.z * w1r_a.z
                         + mk1.x * w1l_b.x + xb.x * w1r_b.x
                         + mk1.z * w1l_b.z + xb.z * w1r_b.z;
        float hbb = mk0.y * w1l_a.y + xa.y * w1r_a.y
                  + mk0.w * w1l_a.w + xa.w * w1r_a.w
                  + mk1.y * w1l_b.y + xb.y * w1r_b.y
                  + mk1.w * w1l_b.w + xb.w * w1r_b.w;
        float h = fmaxf(ha + hbb, 0.0f);
        hl[w][l] = h;

        float a0 = bias2, a1 = 0.f, a2 = 0.f, a3 = 0.f;
        #pragma unroll
        for (int r = 0; r < 16; r += 4) {
            float4 h0 = *(const float4*)&hl[w][r * 4];
            float4 h1 = *(const float4*)&hl[w][r * 4 + 4];
            float4 h2 = *(const float4*)&hl[w][r * 4 + 8];
            float4 h3 = *(const float4*)&hl[w][r * 4 + 12];
            a0 += h0.x * w2q[r].x + h0.y * w2q[r].y + h0.z * w2q[r].z + h0.w * w2q[r].w;
            a1 += h1.x * w2q[r+1].x + h1.y * w2q[r+1].y + h1.z * w2q[r+1].z + h1.w * w2q[r+1].w;
            a2 += h2.x * w2q[r+2].x + h2.y * w2q[r+2].y + h2.z * w2q[r+2].z + h2.w * w2q[r+2].w;
            a3 += h3.x * w2q[r+3].x + h3.y * w2q[r+3].y + h3.z * w2q[r+3].z + h3.w * w2q[r+3].w;
        }
        float val = (a0 + a1) + (a2 + a3);
        if (l < 32) pb[(size_t)n * OUT_C + c] = f2bf(val);   // bf16 message
        else        out[(size_t)n * OUT_C + c] = val;        // fp32 self+bias
    }
}

// ---------------------------------------------------------------------------
// K5: layer-2 neighbor gather over bf16 p, TWO nodes per wave iteration.
// lane = (slot = (l>>4)&3, q = l&15): uint load = 2 bf16 channels;
// 2-level xor reduce; lanes 0-15 commit node A, lanes 16-31 node B.
// ---------------------------------------------------------------------------
__global__ __launch_bounds__(256) void layer2_kernel(
    const u32* __restrict__ pb, const int* __restrict__ csr_src,
    const int2* __restrict__ meta, float* __restrict__ out, int N, int nwaves)
{
    int tid = threadIdx.x;
    int w = tid >> 6;
    int l = tid & 63;
    int waveId = blockIdx.x * 4 + w;
    int slot = (l >> 4) & 3;
    int q = l & 15;

    for (int n = waveId; n < N; n += 2 * nwaves) {
        int nB = n + nwaves;
        bool hasB = (nB < N);
        int2 mA = meta[n];
        int2 mB = hasB ? meta[nB] : make_int2(0, 0);

        float loA = 0.f, hiA = 0.f, loB = 0.f, hiB = 0.f;
        for (int it = slot; it < mA.y; it += 4) {
            int s = csr_src[mA.x + it];
            u32 u = pb[(size_t)s * 16 + q];
            loA += bf_lo(u); hiA += bf_hi(u);
        }
        for (int it = slot; it < mB.y; it += 4) {
            int s = csr_src[mB.x + it];
            u32 u = pb[(size_t)s * 16 + q];
            loB += bf_lo(u); hiB += bf_hi(u);
        }
        loA += __shfl_xor(loA, 16); loA += __shfl_xor(loA, 32);
        hiA += __shfl_xor(hiA, 16); hiA += __shfl_xor(hiA, 32);
        loB += __shfl_xor(loB, 16); loB += __shfl_xor(loB, 32);
        hiB += __shfl_xor(hiB, 16); hiB += __shfl_xor(hiB, 32);

        if (l < 16) {
            float ic = 1.0f / (float)max(mA.y, 1);
            float2* op = (float2*)(out + (size_t)n * OUT_C) + q;
            float2 o = *op;
            o.x += loA * ic; o.y += hiA * ic;
            *op = o;
        } else if (l < 32 && hasB) {
            float ic = 1.0f / (float)max(mB.y, 1);
            float2* op = (float2*)(out + (size_t)nB * OUT_C) + q;
            float2 o = *op;
            o.x += loB * ic; o.y += hiB * ic;
            *op = o;
        }
    }
}

extern "C" void kernel_launch(void* const* d_in, const int* in_sizes, int n_in,
                              void* d_out, int out_size, void* d_ws, size_t ws_size,
                              hipStream_t stream) {
    const float* x   = (const float*)d_in[0];
    const int*   ei  = (const int*)d_in[1];
    const float* W1l = (const float*)d_in[2];
    const float* W1r = (const float*)d_in[3];
    const float* b1  = (const float*)d_in[4];
    const float* W2l = (const float*)d_in[5];
    const float* W2r = (const float*)d_in[6];
    const float* b2  = (const float*)d_in[7];
    float* out = (float*)d_out;

    int N = in_sizes[0] / IN_C;
    int E = in_sizes[1] / 2;
    const int* src = ei;
    const int* dst = ei + E;

    // Workspace: cnt[N] | cursor(16B) | base[N] | meta[N]int2 | erank[E] |
    //            csr_src[E] | pb[N*32]u16
    char* ws = (char*)d_ws;
    size_t off = 0;
    int*   cnt     = (int*)(ws + off);  off += (size_t)N * 4;
    int*   cursor  = (int*)(ws + off);  off += 16;
    int*   base    = (int*)(ws + off);  off += (size_t)N * 4;
    int2*  meta    = (int2*)(ws + off); off += (size_t)N * 8;
    int*   erank   = (int*)(ws + off);  off += (size_t)E * 4;
    int*   csr_src = (int*)(ws + off);  off += (size_t)E * 4;
    u16*   pb      = (u16*)(ws + off);

    hipMemsetAsync(d_ws, 0, (size_t)N * 4 + 16, stream);

    const int blk = 256;
    const int nblocks = 4096;
    const int nwaves = nblocks * 4;

    hist_kernel<<<(E / 8 + blk - 1) / blk, blk, 0, stream>>>(dst, cnt, erank, E);
    base_kernel<<<(N + blk - 1) / blk, blk, 0, stream>>>(cnt, base, meta, cursor, N);
    fill_kernel<<<(E / 8 + blk - 1) / blk, blk, 0, stream>>>(src, dst, erank, base, csr_src, E);
    layer1_kernel<<<nblocks, blk, 0, stream>>>(x, csr_src, meta,
                                               W1l, W1r, b1, W2l, W2r, b2,
                                               pb, out, N, nwaves);
    layer2_kernel<<<nblocks, blk, 0, stream>>>((const u32*)pb, csr_src, meta,
                                               out, N, nwaves);
}

// Round 7
// 272.711 us; speedup vs baseline: 1.0785x; 1.0785x over previous
//
#include <hip/hip_runtime.h>

#define IN_C 8
#define HID_C 64
#define OUT_C 32

typedef unsigned int u32;
typedef unsigned short u16;

__device__ __forceinline__ float bf_lo(u32 u) {
    union { u32 i; float f; } c; c.i = u << 16; return c.f;
}
__device__ __forceinline__ float bf_hi(u32 u) {
    union { u32 i; float f; } c; c.i = u & 0xffff0000u; return c.f;
}
__device__ __forceinline__ u16 f2bf(float v) {          // RNE fp32 -> bf16
    union { float f; u32 i; } c; c.f = v;
    u32 r = c.i + 0x7fffu + ((c.i >> 16) & 1u);
    return (u16)(r >> 16);
}

// ---------------------------------------------------------------------------
// K1: degree histogram + per-edge rank (returning atomics), 8 edges/thread.
// ---------------------------------------------------------------------------
__global__ __launch_bounds__(256) void hist_kernel(
    const int* __restrict__ dst, int* __restrict__ cnt,
    int* __restrict__ erank, int E)
{
    int i = blockIdx.x * blockDim.x + threadIdx.x;
    int e0 = i * 8;
    if (e0 + 7 < E) {
        int4 a = *(const int4*)(dst + e0);
        int4 b = *(const int4*)(dst + e0 + 4);
        int4 ra, rb;
        ra.x = atomicAdd(&cnt[a.x], 1); ra.y = atomicAdd(&cnt[a.y], 1);
        ra.z = atomicAdd(&cnt[a.z], 1); ra.w = atomicAdd(&cnt[a.w], 1);
        rb.x = atomicAdd(&cnt[b.x], 1); rb.y = atomicAdd(&cnt[b.y], 1);
        rb.z = atomicAdd(&cnt[b.z], 1); rb.w = atomicAdd(&cnt[b.w], 1);
        *(int4*)(erank + e0) = ra;
        *(int4*)(erank + e0 + 4) = rb;
    } else {
        for (int e = e0; e < E; ++e)
            erank[e] = atomicAdd(&cnt[dst[e]], 1);
    }
}

// ---------------------------------------------------------------------------
// K2: CSR bases via wave scan; writes base[] (for fill) and meta[]=(base,cnt).
// ---------------------------------------------------------------------------
__global__ __launch_bounds__(256) void base_kernel(
    const int* __restrict__ cnt, int* __restrict__ base,
    int2* __restrict__ meta, int* __restrict__ cursor, int N)
{
    int n = blockIdx.x * blockDim.x + threadIdx.x;
    int lane = threadIdx.x & 63;
    int c = (n < N) ? cnt[n] : 0;

    int v = c;
    #pragma unroll
    for (int off = 1; off < 64; off <<= 1) {
        int t = __shfl_up(v, off);
        if (lane >= off) v += t;
    }
    int total = __shfl(v, 63);
    int waveBase = 0;
    if (lane == 63 && total > 0) waveBase = atomicAdd(cursor, total);
    waveBase = __shfl(waveBase, 63);

    if (n < N) {
        int b = waveBase + v - c;
        base[n] = b;
        meta[n] = make_int2(b, c);
    }
}

// ---------------------------------------------------------------------------
// K3: atomic-free CSR fill, 8 edges/thread, non-temporal scattered stores.
// ---------------------------------------------------------------------------
__global__ __launch_bounds__(256) void fill_kernel(
    const int* __restrict__ src, const int* __restrict__ dst,
    const int* __restrict__ erank, const int* __restrict__ base,
    int* __restrict__ csr_src, int E)
{
    int i = blockIdx.x * blockDim.x + threadIdx.x;
    int e0 = i * 8;
    if (e0 + 7 < E) {
        int4 s0 = *(const int4*)(src + e0), s1 = *(const int4*)(src + e0 + 4);
        int4 d0 = *(const int4*)(dst + e0), d1 = *(const int4*)(dst + e0 + 4);
        int4 r0 = *(const int4*)(erank + e0), r1 = *(const int4*)(erank + e0 + 4);
        __builtin_nontemporal_store(s0.x, &csr_src[base[d0.x] + r0.x]);
        __builtin_nontemporal_store(s0.y, &csr_src[base[d0.y] + r0.y]);
        __builtin_nontemporal_store(s0.z, &csr_src[base[d0.z] + r0.z]);
        __builtin_nontemporal_store(s0.w, &csr_src[base[d0.w] + r0.w]);
        __builtin_nontemporal_store(s1.x, &csr_src[base[d1.x] + r1.x]);
        __builtin_nontemporal_store(s1.y, &csr_src[base[d1.y] + r1.y]);
        __builtin_nontemporal_store(s1.z, &csr_src[base[d1.z] + r1.z]);
        __builtin_nontemporal_store(s1.w, &csr_src[base[d1.w] + r1.w]);
    } else {
        for (int e = e0; e < E; ++e)
            __builtin_nontemporal_store(src[e], &csr_src[base[dst[e]] + erank[e]]);
    }
}

// ---------------------------------------------------------------------------
// K4: fused layer-1 + both layer-2 projections. One wave per node,
// grid-strided, no barriers (hl is wave-local; DS is wave-program-order).
// r5 core (float4 gather slot=l>>1,q=l&1; xor-tree mean) + 3-deep software
// pipeline: prefetch next meta + self-row at loop top, next csr-index +
// first-batch x float4 before the W2 dot. Steady state exposes ~no global
// latency for deg<=32 nodes (99.98% at Poisson-16).
// ---------------------------------------------------------------------------
__global__ __launch_bounds__(256) void layer1_kernel(
    const float* __restrict__ x, const int* __restrict__ csr_src,
    const int2* __restrict__ meta,
    const float* __restrict__ W1l, const float* __restrict__ W1r,
    const float* __restrict__ b1,
    const float* __restrict__ W2l, const float* __restrict__ W2r,
    const float* __restrict__ b2,
    u16* __restrict__ pb, float* __restrict__ out, int N, int nwaves)
{
    __shared__ float hl[4][HID_C];
    int tid = threadIdx.x;
    int w = tid >> 6;
    int l = tid & 63;
    int waveId = blockIdx.x * 4 + w;

    float4 w1l_a = *(const float4*)(W1l + l * IN_C);
    float4 w1l_b = *(const float4*)(W1l + l * IN_C + 4);
    float4 w1r_a = *(const float4*)(W1r + l * IN_C);
    float4 w1r_b = *(const float4*)(W1r + l * IN_C + 4);
    int c = l & 31;
    const float* W2 = (l < 32) ? W2l : W2r;
    float4 w2q[16];
    #pragma unroll
    for (int r = 0; r < 16; ++r)
        w2q[r] = *(const float4*)(W2 + c * HID_C + r * 4);
    float bias1 = b1[l];
    float bias2 = (l < 32) ? 0.0f : b2[c];

    int slot = l >> 1;
    int q = l & 1;

    // ---- pipeline prologue ----
    int n = waveId;
    int2 m = make_int2(0, 0);
    float4 v0 = make_float4(0.f, 0.f, 0.f, 0.f);
    float4 xa = v0, xb = v0;
    if (n < N) {
        m = meta[n];
        xa = ((const float4*)(x + (size_t)n * IN_C))[0];
        xb = ((const float4*)(x + (size_t)n * IN_C))[1];
        if (slot < m.y)
            v0 = ((const float4*)(x + (size_t)csr_src[m.x + slot] * IN_C))[q];
    }

    while (n < N) {
        int nn = n + nwaves;
        int2 mn = make_int2(0, 0);
        float4 xan = make_float4(0.f, 0.f, 0.f, 0.f), xbn = xan;
        if (nn < N) {                       // prefetch next meta + self row
            mn = meta[nn];
            xan = ((const float4*)(x + (size_t)nn * IN_C))[0];
            xbn = ((const float4*)(x + (size_t)nn * IN_C))[1];
        }

        // gather: first batch is the prefetched v0; remainder (rare) chained
        float4 g = v0;
        for (int it = slot + 32; it < m.y; it += 32) {
            int s = csr_src[m.x + it];
            float4 v = ((const float4*)(x + (size_t)s * IN_C))[q];
            g.x += v.x; g.y += v.y; g.z += v.z; g.w += v.w;
        }

        // prefetch next node's first-batch neighbor row (csr -> x chain
        // hides under the reduce + W2 dot below)
        float4 v0n = make_float4(0.f, 0.f, 0.f, 0.f);
        if (slot < mn.y)
            v0n = ((const float4*)(x + (size_t)csr_src[mn.x + slot] * IN_C))[q];

        float icnt = 1.0f / (float)max(m.y, 1);
        #pragma unroll
        for (int mm = 2; mm <= 32; mm <<= 1) {
            g.x += __shfl_xor(g.x, mm);
            g.y += __shfl_xor(g.y, mm);
            g.z += __shfl_xor(g.z, mm);
            g.w += __shfl_xor(g.w, mm);
        }
        g.x *= icnt; g.y *= icnt; g.z *= icnt; g.w *= icnt;
        float4 o;
        o.x = __shfl_xor(g.x, 1);
        o.y = __shfl_xor(g.y, 1);
        o.z = __shfl_xor(g.z, 1);
        o.w = __shfl_xor(g.w, 1);
        float4 mka = q ? o : g;             // mean channels 0-3
        float4 mkb = q ? g : o;             // mean channels 4-7

        float ha = bias1 + mka.x * w1l_a.x + xa.x * w1r_a.x
                         + mka.z * w1l_a.z + xa.z * w1r_a.z
                         + mkb.x * w1l_b.x + xb.x * w1r_b.x
                         + mkb.z * w1l_b.z + xb.z * w1r_b.z;
        float hb = mka.y * w1l_a.y + xa.y * w1r_a.y
                 + mka.w * w1l_a.w + xa.w * w1r_a.w
                 + mkb.y * w1l_b.y + xb.y * w1r_b.y
                 + mkb.w * w1l_b.w + xb.w * w1r_b.w;
        float h = fmaxf(ha + hb, 0.0f);
        hl[w][l] = h;                       // wave-local, in-order DS

        float a0 = bias2, a1 = 0.f, a2 = 0.f, a3 = 0.f;
        #pragma unroll
        for (int r = 0; r < 16; r += 4) {
            float4 h0 = *(const float4*)&hl[w][r * 4];
            float4 h1 = *(const float4*)&hl[w][r * 4 + 4];
            float4 h2 = *(const float4*)&hl[w][r * 4 + 8];
            float4 h3 = *(const float4*)&hl[w][r * 4 + 12];
            a0 += h0.x * w2q[r].x + h0.y * w2q[r].y + h0.z * w2q[r].z + h0.w * w2q[r].w;
            a1 += h1.x * w2q[r+1].x + h1.y * w2q[r+1].y + h1.z * w2q[r+1].z + h1.w * w2q[r+1].w;
            a2 += h2.x * w2q[r+2].x + h2.y * w2q[r+2].y + h2.z * w2q[r+2].z + h2.w * w2q[r+2].w;
            a3 += h3.x * w2q[r+3].x + h3.y * w2q[r+3].y + h3.z * w2q[r+3].z + h3.w * w2q[r+3].w;
        }
        float val = (a0 + a1) + (a2 + a3);
        if (l < 32) pb[(size_t)n * OUT_C + c] = f2bf(val);   // bf16 message
        else        out[(size_t)n * OUT_C + c] = val;        // fp32 self+bias

        n = nn; m = mn; v0 = v0n; xa = xan; xb = xbn;
    }
}

// ---------------------------------------------------------------------------
// K5: layer-2 neighbor gather over bf16 p rows. One wave per node,
// grid-strided, pipelined like K4. lane = (slot = l>>2 in 0..15, r = l&3):
// one uint4 load = 8 bf16 channels; deg<=16 in ONE batch (~57% of nodes),
// remainder batch's csr load is independent of the first. 4-level xor
// reduce over slot bits; lanes 0-3 RMW the fp32 out row.
// ---------------------------------------------------------------------------
__global__ __launch_bounds__(256) void layer2_kernel(
    const uint4* __restrict__ pb4, const int* __restrict__ csr_src,
    const int2* __restrict__ meta, float* __restrict__ out, int N, int nwaves)
{
    int tid = threadIdx.x;
    int w = tid >> 6;
    int l = tid & 63;
    int waveId = blockIdx.x * 4 + w;
    int slot = l >> 2;
    int r = l & 3;

    // ---- pipeline prologue ----
    int n = waveId;
    int2 m = make_int2(0, 0);
    uint4 v0 = make_uint4(0u, 0u, 0u, 0u);
    if (n < N) {
        m = meta[n];
        if (slot < m.y)
            v0 = pb4[(size_t)csr_src[m.x + slot] * 4 + r];
    }

    while (n < N) {
        int nn = n + nwaves;
        int2 mn = make_int2(0, 0);
        if (nn < N) mn = meta[nn];

        float s0 = bf_lo(v0.x), s1 = bf_hi(v0.x);
        float s2 = bf_lo(v0.y), s3 = bf_hi(v0.y);
        float s4 = bf_lo(v0.z), s5 = bf_hi(v0.z);
        float s6 = bf_lo(v0.w), s7 = bf_hi(v0.w);
        for (int it = slot + 16; it < m.y; it += 16) {
            uint4 v = pb4[(size_t)csr_src[m.x + it] * 4 + r];
            s0 += bf_lo(v.x); s1 += bf_hi(v.x);
            s2 += bf_lo(v.y); s3 += bf_hi(v.y);
            s4 += bf_lo(v.z); s5 += bf_hi(v.z);
            s6 += bf_lo(v.w); s7 += bf_hi(v.w);
        }

        // prefetch next node's first batch (hides under reduce + RMW)
        uint4 v0n = make_uint4(0u, 0u, 0u, 0u);
        if (slot < mn.y)
            v0n = pb4[(size_t)csr_src[mn.x + slot] * 4 + r];

        #pragma unroll
        for (int mm = 4; mm <= 32; mm <<= 1) {
            s0 += __shfl_xor(s0, mm); s1 += __shfl_xor(s1, mm);
            s2 += __shfl_xor(s2, mm); s3 += __shfl_xor(s3, mm);
            s4 += __shfl_xor(s4, mm); s5 += __shfl_xor(s5, mm);
            s6 += __shfl_xor(s6, mm); s7 += __shfl_xor(s7, mm);
        }

        if (l < 4) {                       // lane l == r, slot 0
            float ic = 1.0f / (float)max(m.y, 1);
            float4* op = (float4*)(out + (size_t)n * OUT_C) + l * 2;
            float4 o0 = op[0], o1 = op[1];
            o0.x += s0 * ic; o0.y += s1 * ic; o0.z += s2 * ic; o0.w += s3 * ic;
            o1.x += s4 * ic; o1.y += s5 * ic; o1.z += s6 * ic; o1.w += s7 * ic;
            op[0] = o0; op[1] = o1;
        }

        n = nn; m = mn; v0 = v0n;
    }
}

extern "C" void kernel_launch(void* const* d_in, const int* in_sizes, int n_in,
                              void* d_out, int out_size, void* d_ws, size_t ws_size,
                              hipStream_t stream) {
    const float* x   = (const float*)d_in[0];
    const int*   ei  = (const int*)d_in[1];
    const float* W1l = (const float*)d_in[2];
    const float* W1r = (const float*)d_in[3];
    const float* b1  = (const float*)d_in[4];
    const float* W2l = (const float*)d_in[5];
    const float* W2r = (const float*)d_in[6];
    const float* b2  = (const float*)d_in[7];
    float* out = (float*)d_out;

    int N = in_sizes[0] / IN_C;
    int E = in_sizes[1] / 2;
    const int* src = ei;
    const int* dst = ei + E;

    // Workspace: cnt[N] | cursor(16B) | base[N] | meta[N]int2 | erank[E] |
    //            csr_src[E] | pb[N*32]u16 (16B-aligned)
    char* ws = (char*)d_ws;
    size_t off = 0;
    int*   cnt     = (int*)(ws + off);  off += (size_t)N * 4;
    int*   cursor  = (int*)(ws + off);  off += 16;
    int*   base    = (int*)(ws + off);  off += (size_t)N * 4;
    int2*  meta    = (int2*)(ws + off); off += (size_t)N * 8;
    int*   erank   = (int*)(ws + off);  off += (size_t)E * 4;
    int*   csr_src = (int*)(ws + off);  off += (size_t)E * 4;
    u16*   pb      = (u16*)(ws + off);

    hipMemsetAsync(d_ws, 0, (size_t)N * 4 + 16, stream);

    const int blk = 256;
    const int nblocks = 2048;              // one fully-resident round
    const int nwaves = nblocks * 4;

    hist_kernel<<<(E / 8 + blk - 1) / blk, blk, 0, stream>>>(dst, cnt, erank, E);
    base_kernel<<<(N + blk - 1) / blk, blk, 0, stream>>>(cnt, base, meta, cursor, N);
    fill_kernel<<<(E / 8 + blk - 1) / blk, blk, 0, stream>>>(src, dst, erank, base, csr_src, E);
    layer1_kernel<<<nblocks, blk, 0, stream>>>(x, csr_src, meta,
                                               W1l, W1r, b1, W2l, W2r, b2,
                                               pb, out, N, nwaves);
    layer2_kernel<<<nblocks, blk, 0, stream>>>((const uint4*)pb, csr_src, meta,
                                               out, N, nwaves);
}

// Round 8
// 272.076 us; speedup vs baseline: 1.0810x; 1.0023x over previous
//
#include <hip/hip_runtime.h>

#define IN_C 8
#define HID_C 64
#define OUT_C 32

typedef unsigned int u32;
typedef unsigned short u16;

__device__ __forceinline__ float bf_lo(u32 u) {
    union { u32 i; float f; } c; c.i = u << 16; return c.f;
}
__device__ __forceinline__ float bf_hi(u32 u) {
    union { u32 i; float f; } c; c.i = u & 0xffff0000u; return c.f;
}
__device__ __forceinline__ u16 f2bf(float v) {          // RNE fp32 -> bf16
    union { float f; u32 i; } c; c.f = v;
    u32 r = c.i + 0x7fffu + ((c.i >> 16) & 1u);
    return (u16)(r >> 16);
}
__device__ __forceinline__ float rdlane(float v, int k) { // broadcast lane k
    return __uint_as_float(__builtin_amdgcn_readlane(__float_as_uint(v), k));
}

// ---------------------------------------------------------------------------
// K1: degree histogram + per-edge rank (returning atomics), 8 edges/thread.
// ---------------------------------------------------------------------------
__global__ __launch_bounds__(256) void hist_kernel(
    const int* __restrict__ dst, int* __restrict__ cnt,
    int* __restrict__ erank, int E)
{
    int i = blockIdx.x * blockDim.x + threadIdx.x;
    int e0 = i * 8;
    if (e0 + 7 < E) {
        int4 a = *(const int4*)(dst + e0);
        int4 b = *(const int4*)(dst + e0 + 4);
        int4 ra, rb;
        ra.x = atomicAdd(&cnt[a.x], 1); ra.y = atomicAdd(&cnt[a.y], 1);
        ra.z = atomicAdd(&cnt[a.z], 1); ra.w = atomicAdd(&cnt[a.w], 1);
        rb.x = atomicAdd(&cnt[b.x], 1); rb.y = atomicAdd(&cnt[b.y], 1);
        rb.z = atomicAdd(&cnt[b.z], 1); rb.w = atomicAdd(&cnt[b.w], 1);
        *(int4*)(erank + e0) = ra;
        *(int4*)(erank + e0 + 4) = rb;
    } else {
        for (int e = e0; e < E; ++e)
            erank[e] = atomicAdd(&cnt[dst[e]], 1);
    }
}

// ---------------------------------------------------------------------------
// K2: CSR bases via wave scan; writes base[] (for fill) and meta[]=(base,cnt).
// ---------------------------------------------------------------------------
__global__ __launch_bounds__(256) void base_kernel(
    const int* __restrict__ cnt, int* __restrict__ base,
    int2* __restrict__ meta, int* __restrict__ cursor, int N)
{
    int n = blockIdx.x * blockDim.x + threadIdx.x;
    int lane = threadIdx.x & 63;
    int c = (n < N) ? cnt[n] : 0;

    int v = c;
    #pragma unroll
    for (int off = 1; off < 64; off <<= 1) {
        int t = __shfl_up(v, off);
        if (lane >= off) v += t;
    }
    int total = __shfl(v, 63);
    int waveBase = 0;
    if (lane == 63 && total > 0) waveBase = atomicAdd(cursor, total);
    waveBase = __shfl(waveBase, 63);

    if (n < N) {
        int b = waveBase + v - c;
        base[n] = b;
        meta[n] = make_int2(b, c);
    }
}

// ---------------------------------------------------------------------------
// K3: atomic-free CSR fill, 8 edges/thread, non-temporal scattered stores.
// ---------------------------------------------------------------------------
__global__ __launch_bounds__(256) void fill_kernel(
    const int* __restrict__ src, const int* __restrict__ dst,
    const int* __restrict__ erank, const int* __restrict__ base,
    int* __restrict__ csr_src, int E)
{
    int i = blockIdx.x * blockDim.x + threadIdx.x;
    int e0 = i * 8;
    if (e0 + 7 < E) {
        int4 s0 = *(const int4*)(src + e0), s1 = *(const int4*)(src + e0 + 4);
        int4 d0 = *(const int4*)(dst + e0), d1 = *(const int4*)(dst + e0 + 4);
        int4 r0 = *(const int4*)(erank + e0), r1 = *(const int4*)(erank + e0 + 4);
        __builtin_nontemporal_store(s0.x, &csr_src[base[d0.x] + r0.x]);
        __builtin_nontemporal_store(s0.y, &csr_src[base[d0.y] + r0.y]);
        __builtin_nontemporal_store(s0.z, &csr_src[base[d0.z] + r0.z]);
        __builtin_nontemporal_store(s0.w, &csr_src[base[d0.w] + r0.w]);
        __builtin_nontemporal_store(s1.x, &csr_src[base[d1.x] + r1.x]);
        __builtin_nontemporal_store(s1.y, &csr_src[base[d1.y] + r1.y]);
        __builtin_nontemporal_store(s1.z, &csr_src[base[d1.z] + r1.z]);
        __builtin_nontemporal_store(s1.w, &csr_src[base[d1.w] + r1.w]);
    } else {
        for (int e = e0; e < E; ++e)
            __builtin_nontemporal_store(src[e], &csr_src[base[dst[e]] + erank[e]]);
    }
}

// ---------------------------------------------------------------------------
// K4: fused layer-1 + both layer-2 projections. One wave per node,
// grid-strided, ZERO LDS. DS ops cut to 14/node:
//   gather: (slot = l>>2 in 0..15, q = l&3) float2 loads; reduce over slot
//   bits {4,8,16,32} = 8 swizzles; assemble 8 mean chans via mask-1 (2) +
//   mask-2 (4) exchanges.
//   W2 dot: v_readlane broadcasts of h (per-SIMD pipe, not shared LDS pipe),
//   SGPR-operand FMAs, 4 accumulator strands.
// 3-deep pipeline retained (meta/self-row/first-batch prefetch).
// ---------------------------------------------------------------------------
__global__ __launch_bounds__(256) void layer1_kernel(
    const float* __restrict__ x, const int* __restrict__ csr_src,
    const int2* __restrict__ meta,
    const float* __restrict__ W1l, const float* __restrict__ W1r,
    const float* __restrict__ b1,
    const float* __restrict__ W2l, const float* __restrict__ W2r,
    const float* __restrict__ b2,
    u16* __restrict__ pb, float* __restrict__ out, int N, int nwaves)
{
    int tid = threadIdx.x;
    int l = tid & 63;
    int waveId = blockIdx.x * 4 + (tid >> 6);

    float4 w1l_a = *(const float4*)(W1l + l * IN_C);
    float4 w1l_b = *(const float4*)(W1l + l * IN_C + 4);
    float4 w1r_a = *(const float4*)(W1r + l * IN_C);
    float4 w1r_b = *(const float4*)(W1r + l * IN_C + 4);
    int c = l & 31;
    const float* W2 = (l < 32) ? W2l : W2r;
    float4 w2q[16];
    #pragma unroll
    for (int r = 0; r < 16; ++r)
        w2q[r] = *(const float4*)(W2 + c * HID_C + r * 4);
    float bias1 = b1[l];
    float bias2 = (l < 32) ? 0.0f : b2[c];

    int slot = l >> 2;        // 0..15
    int q = l & 3;            // float2 index within the 8-float row

    // ---- pipeline prologue ----
    int n = waveId;
    int2 m = make_int2(0, 0);
    float2 v0 = make_float2(0.f, 0.f);
    float4 xa = make_float4(0.f, 0.f, 0.f, 0.f), xb = xa;
    if (n < N) {
        m = meta[n];
        xa = ((const float4*)(x + (size_t)n * IN_C))[0];
        xb = ((const float4*)(x + (size_t)n * IN_C))[1];
        if (slot < m.y)
            v0 = ((const float2*)(x + (size_t)csr_src[m.x + slot] * IN_C))[q];
    }

    while (n < N) {
        int nn = n + nwaves;
        int2 mn = make_int2(0, 0);
        float4 xan = make_float4(0.f, 0.f, 0.f, 0.f), xbn = xan;
        if (nn < N) {                       // prefetch next meta + self row
            mn = meta[nn];
            xan = ((const float4*)(x + (size_t)nn * IN_C))[0];
            xbn = ((const float4*)(x + (size_t)nn * IN_C))[1];
        }

        // gather: first batch prefetched; deg 17..32 adds one independent batch
        float2 g = v0;
        for (int it = slot + 16; it < m.y; it += 16) {
            float2 v = ((const float2*)(x + (size_t)csr_src[m.x + it] * IN_C))[q];
            g.x += v.x; g.y += v.y;
        }

        // prefetch next node's first batch (hides under reduce + dot)
        float2 v0n = make_float2(0.f, 0.f);
        if (slot < mn.y)
            v0n = ((const float2*)(x + (size_t)csr_src[mn.x + slot] * IN_C))[q];

        // reduce over slot bits: 4 levels x 2 comps = 8 swizzles
        float icnt = 1.0f / (float)max(m.y, 1);
        #pragma unroll
        for (int mm = 4; mm <= 32; mm <<= 1) {
            g.x += __shfl_xor(g.x, mm);
            g.y += __shfl_xor(g.y, mm);
        }
        g.x *= icnt; g.y *= icnt;

        // assemble mean[0..7]: mask-1 exchange (2) + mask-2 exchange (4)
        float2 e1;
        e1.x = __shfl_xor(g.x, 1);
        e1.y = __shfl_xor(g.y, 1);
        float4 gg = (q & 1) ? make_float4(e1.x, e1.y, g.x, g.y)
                            : make_float4(g.x, g.y, e1.x, e1.y);
        float4 e2;
        e2.x = __shfl_xor(gg.x, 2);
        e2.y = __shfl_xor(gg.y, 2);
        e2.z = __shfl_xor(gg.z, 2);
        e2.w = __shfl_xor(gg.w, 2);
        float4 mka = (q & 2) ? e2 : gg;     // mean channels 0-3
        float4 mkb = (q & 2) ? gg : e2;     // mean channels 4-7

        float ha = bias1 + mka.x * w1l_a.x + xa.x * w1r_a.x
                         + mka.z * w1l_a.z + xa.z * w1r_a.z
                         + mkb.x * w1l_b.x + xb.x * w1r_b.x
                         + mkb.z * w1l_b.z + xb.z * w1r_b.z;
        float hb = mka.y * w1l_a.y + xa.y * w1r_a.y
                 + mka.w * w1l_a.w + xa.w * w1r_a.w
                 + mkb.y * w1l_b.y + xb.y * w1r_b.y
                 + mkb.w * w1l_b.w + xb.w * w1r_b.w;
        float h = fmaxf(ha + hb, 0.0f);

        // W2 dot via readlane broadcasts: no LDS, 4 strands of 16 FMAs
        float a0 = bias2, a1 = 0.f, a2 = 0.f, a3 = 0.f;
        #pragma unroll
        for (int r = 0; r < 16; ++r) {
            float4 wv = w2q[r];
            a0 += rdlane(h, 4 * r + 0) * wv.x;
            a1 += rdlane(h, 4 * r + 1) * wv.y;
            a2 += rdlane(h, 4 * r + 2) * wv.z;
            a3 += rdlane(h, 4 * r + 3) * wv.w;
        }
        float val = (a0 + a1) + (a2 + a3);
        if (l < 32) pb[(size_t)n * OUT_C + c] = f2bf(val);   // bf16 message
        else        out[(size_t)n * OUT_C + c] = val;        // fp32 self+bias

        n = nn; m = mn; v0 = v0n; xa = xan; xb = xbn;
    }
}

// ---------------------------------------------------------------------------
// K5: layer-2 neighbor gather over bf16 p rows. One wave per node,
// grid-strided, pipelined. lane = (slot = l>>2 in 0..15, r = l&3):
// one uint4 load = 8 bf16 channels; 4-level xor reduce; lanes 0-3 RMW out.
// ---------------------------------------------------------------------------
__global__ __launch_bounds__(256) void layer2_kernel(
    const uint4* __restrict__ pb4, const int* __restrict__ csr_src,
    const int2* __restrict__ meta, float* __restrict__ out, int N, int nwaves)
{
    int tid = threadIdx.x;
    int w = tid >> 6;
    int l = tid & 63;
    int waveId = blockIdx.x * 4 + w;
    int slot = l >> 2;
    int r = l & 3;

    // ---- pipeline prologue ----
    int n = waveId;
    int2 m = make_int2(0, 0);
    uint4 v0 = make_uint4(0u, 0u, 0u, 0u);
    if (n < N) {
        m = meta[n];
        if (slot < m.y)
            v0 = pb4[(size_t)csr_src[m.x + slot] * 4 + r];
    }

    while (n < N) {
        int nn = n + nwaves;
        int2 mn = make_int2(0, 0);
        if (nn < N) mn = meta[nn];

        float s0 = bf_lo(v0.x), s1 = bf_hi(v0.x);
        float s2 = bf_lo(v0.y), s3 = bf_hi(v0.y);
        float s4 = bf_lo(v0.z), s5 = bf_hi(v0.z);
        float s6 = bf_lo(v0.w), s7 = bf_hi(v0.w);
        for (int it = slot + 16; it < m.y; it += 16) {
            uint4 v = pb4[(size_t)csr_src[m.x + it] * 4 + r];
            s0 += bf_lo(v.x); s1 += bf_hi(v.x);
            s2 += bf_lo(v.y); s3 += bf_hi(v.y);
            s4 += bf_lo(v.z); s5 += bf_hi(v.z);
            s6 += bf_lo(v.w); s7 += bf_hi(v.w);
        }

        // prefetch next node's first batch (hides under reduce + RMW)
        uint4 v0n = make_uint4(0u, 0u, 0u, 0u);
        if (slot < mn.y)
            v0n = pb4[(size_t)csr_src[mn.x + slot] * 4 + r];

        #pragma unroll
        for (int mm = 4; mm <= 32; mm <<= 1) {
            s0 += __shfl_xor(s0, mm); s1 += __shfl_xor(s1, mm);
            s2 += __shfl_xor(s2, mm); s3 += __shfl_xor(s3, mm);
            s4 += __shfl_xor(s4, mm); s5 += __shfl_xor(s5, mm);
            s6 += __shfl_xor(s6, mm); s7 += __shfl_xor(s7, mm);
        }

        if (l < 4) {                       // lane l == r, slot 0
            float ic = 1.0f / (float)max(m.y, 1);
            float4* op = (float4*)(out + (size_t)n * OUT_C) + l * 2;
            float4 o0 = op[0], o1 = op[1];
            o0.x += s0 * ic; o0.y += s1 * ic; o0.z += s2 * ic; o0.w += s3 * ic;
            o1.x += s4 * ic; o1.y += s5 * ic; o1.z += s6 * ic; o1.w += s7 * ic;
            op[0] = o0; op[1] = o1;
        }

        n = nn; m = mn; v0 = v0n;
    }
}

extern "C" void kernel_launch(void* const* d_in, const int* in_sizes, int n_in,
                              void* d_out, int out_size, void* d_ws, size_t ws_size,
                              hipStream_t stream) {
    const float* x   = (const float*)d_in[0];
    const int*   ei  = (const int*)d_in[1];
    const float* W1l = (const float*)d_in[2];
    const float* W1r = (const float*)d_in[3];
    const float* b1  = (const float*)d_in[4];
    const float* W2l = (const float*)d_in[5];
    const float* W2r = (const float*)d_in[6];
    const float* b2  = (const float*)d_in[7];
    float* out = (float*)d_out;

    int N = in_sizes[0] / IN_C;
    int E = in_sizes[1] / 2;
    const int* src = ei;
    const int* dst = ei + E;

    // Workspace: cnt[N] | cursor(16B) | base[N] | meta[N]int2 | erank[E] |
    //            csr_src[E] | pb[N*32]u16 (16B-aligned)
    char* ws = (char*)d_ws;
    size_t off = 0;
    int*   cnt     = (int*)(ws + off);  off += (size_t)N * 4;
    int*   cursor  = (int*)(ws + off);  off += 16;
    int*   base    = (int*)(ws + off);  off += (size_t)N * 4;
    int2*  meta    = (int2*)(ws + off); off += (size_t)N * 8;
    int*   erank   = (int*)(ws + off);  off += (size_t)E * 4;
    int*   csr_src = (int*)(ws + off);  off += (size_t)E * 4;
    u16*   pb      = (u16*)(ws + off);

    hipMemsetAsync(d_ws, 0, (size_t)N * 4 + 16, stream);

    const int blk = 256;
    const int nblocks = 2048;
    const int nwaves = nblocks * 4;

    hist_kernel<<<(E / 8 + blk - 1) / blk, blk, 0, stream>>>(dst, cnt, erank, E);
    base_kernel<<<(N + blk - 1) / blk, blk, 0, stream>>>(cnt, base, meta, cursor, N);
    fill_kernel<<<(E / 8 + blk - 1) / blk, blk, 0, stream>>>(src, dst, erank, base, csr_src, E);
    layer1_kernel<<<nblocks, blk, 0, stream>>>(x, csr_src, meta,
                                               W1l, W1r, b1, W2l, W2r, b2,
                                               pb, out, N, nwaves);
    layer2_kernel<<<nblocks, blk, 0, stream>>>((const uint4*)pb, csr_src, meta,
                                               out, N, nwaves);
}